// Round 6
// baseline (413.647 us; speedup 1.0000x reference)
//
#include <hip/hip_runtime.h>
#include <hip/hip_bf16.h>
#include <stdint.h>

// GPT causal self-attention block. B=8, T=1024, C=768, H=8, D=96. f32 I/O.
// bf16 MFMA pipeline with fp32 accumulation. Causal mask input ignored.
//
// R5: ZERO-SYNC REGISTER STREAMING. Rounds 1-4 showed the barrier-ganged
// LDS pipeline is serialization-bound (all resource floors ~4x under the
// measured time). This version has NO barriers, NO LDS, NO waitcnt: each
// wave streams its operand fragments global->register (L2-resident) with a
// 3-bank software pipeline and owns an independent 64x64 output tile.
// Attention waves stream K/V fragments directly and exit at their own
// causal bound (no more idling in a partner chunk's barriers).

typedef unsigned short ushort_t;
typedef __attribute__((ext_vector_type(8))) short short8;     // 8 bf16 = 4 VGPRs
typedef __attribute__((ext_vector_type(4))) float floatx4;    // MFMA C/D frag
typedef __attribute__((ext_vector_type(4))) unsigned short ushort4v;

#define MFMA16(a, b, c) __builtin_amdgcn_mfma_f32_16x16x32_bf16(a, b, c, 0, 0, 0)
#define NEG_BIG (-1e30f)

__device__ __forceinline__ unsigned short f2bf(float f) {
  union { float f; unsigned int u; } v; v.f = f;
  unsigned int r = (v.u + 0x7FFFu + ((v.u >> 16) & 1u)) >> 16;  // RNE
  return (unsigned short)r;
}

__device__ __forceinline__ unsigned int packbf2(float a, float b) {
  // low 16 = bf16(a), high 16 = bf16(b)  (v_cvt_pk_bf16_f32)
  union { __hip_bfloat162 h; unsigned int u; } cv;
  cv.h = __float22bfloat162_rn(make_float2(a, b));
  return cv.u;
}

// ---------------------------------------------------------------------------
// Fused f32->bf16 conversion for x, Wqkv, Wproj in one launch.
// ---------------------------------------------------------------------------
__global__ __launch_bounds__(256) void cvt3(
    const float* __restrict__ x, const float* __restrict__ wa,
    const float* __restrict__ wp, ushort_t* __restrict__ xb,
    ushort_t* __restrict__ wab, ushort_t* __restrict__ wpb)
{
  const int n1 = (8192 * 768) / 4, n2 = (2304 * 768) / 4;
  int i = blockIdx.x * 256 + threadIdx.x;
  const float* in; ushort_t* out;
  if (i < n1)            { in = x;  out = xb; }
  else if (i < n1 + n2)  { in = wa; out = wab; i -= n1; }
  else                   { in = wp; out = wpb; i -= (n1 + n2); }
  float4 v = *(const float4*)(in + (size_t)i * 4);
  ushort4v o;
  o.x = f2bf(v.x); o.y = f2bf(v.y); o.z = f2bf(v.z); o.w = f2bf(v.w);
  *(ushort4v*)(out + (size_t)i * 4) = o;
}

// ---------------------------------------------------------------------------
// Streaming GEMM core: 1 wave per block, 64x64 output tile, K=768.
// Fragments loaded straight from global (L2) with immediate offsets along K;
// 3 register banks give ~2 compute-phases of load slack. No LDS, no sync.
// ---------------------------------------------------------------------------
#define SLD(AA, BB, KO)                                                \
  do {                                                                 \
    _Pragma("unroll")                                                  \
    for (int t_ = 0; t_ < 4; ++t_) {                                   \
      AA[t_] = *(const short8*)(pA[t_] + (KO));                        \
      BB[t_] = *(const short8*)(pB[t_] + (KO));                        \
    }                                                                  \
  } while (0)

#define SCOMP(AA, BB)                                                  \
  do {                                                                 \
    __builtin_amdgcn_s_setprio(1);                                     \
    _Pragma("unroll")                                                  \
    for (int tm = 0; tm < 4; ++tm)                                     \
      _Pragma("unroll")                                                \
      for (int tn = 0; tn < 4; ++tn)                                   \
        acc[tm][tn] = MFMA16(AA[tm], BB[tn], acc[tm][tn]);             \
    __builtin_amdgcn_s_setprio(0);                                     \
  } while (0)

// declares tid/l15/quad/m0/n0/acc and runs the full K loop
#define SGEMM_BODY(ABASE, WBASE)                                       \
  const int tid  = threadIdx.x;                                        \
  const int l15  = tid & 15;                                           \
  const int quad = tid >> 4;                                           \
  const int m0 = blockIdx.x * 64;                                      \
  const int n0 = blockIdx.y * 64;                                      \
  floatx4 acc[4][4] = {};                                              \
  const ushort_t* pA[4];                                               \
  const ushort_t* pB[4];                                               \
  _Pragma("unroll")                                                    \
  for (int t_ = 0; t_ < 4; ++t_) {                                     \
    pA[t_] = (ABASE) + (size_t)(m0 + t_ * 16 + l15) * 768 + quad * 8;  \
    pB[t_] = (WBASE) + (size_t)(n0 + t_ * 16 + l15) * 768 + quad * 8;  \
  }                                                                    \
  short8 a0[4], b0[4], a1[4], b1[4], a2[4], b2[4];                     \
  SLD(a0, b0, 0);                                                      \
  SLD(a1, b1, 32);                                                     \
  _Pragma("unroll")                                                    \
  for (int kk = 0; kk < 768; kk += 96) {                               \
    SLD(a2, b2, kk + 64);                                              \
    SCOMP(a0, b0);                                                     \
    if (kk + 96 < 768) SLD(a0, b0, kk + 96);                           \
    SCOMP(a1, b1);                                                     \
    if (kk + 128 < 768) SLD(a1, b1, kk + 128);                         \
    SCOMP(a2, b2);                                                     \
  }

// ---------------------------------------------------------------------------
// QKV GEMM: qkv = x @ Wqkv^T + b. Q columns pre-scaled by (1/sqrt(96))*log2e.
// Writes q,k into QK (row stride 1536) and v TRANSPOSED into VT[b][h][d][T]
// with time index sigma-permuted within each 64-block (attention needs no
// cross-lane P exchange).
// ---------------------------------------------------------------------------
__global__ __launch_bounds__(64, 2) void gemm_qkv(
    const ushort_t* __restrict__ A,   // 8192 x 768 bf16 (x)
    const ushort_t* __restrict__ W,   // 2304 x 768 bf16
    const float* __restrict__ bias,   // 2304 f32
    ushort_t* __restrict__ QK,        // 8192 x 1536 bf16
    ushort_t* __restrict__ VT)        // (64 bh) x 96 x 1024 bf16 (perm cols)
{
  SGEMM_BODY(A, W);

  const float QSCALE = 0.10206207261596577f * 1.4426950408889634f;

#pragma unroll
  for (int tn = 0; tn < 4; ++tn) {
    const int gc = n0 + tn * 16 + l15;
    const float bv = bias[gc];
    const bool isv = (gc >= 1536);          // whole 16-col tile same side
    const bool isq = (gc < 768);
    const int hh = (gc - 1536) / 96, dd = (gc - 1536) % 96;
#pragma unroll
    for (int tm = 0; tm < 4; ++tm) {
      const int gr = m0 + tm * 16 + quad * 4;
#pragma unroll
      for (int r = 0; r < 4; ++r) {
        float val = acc[tm][tn][r] + bv;
        const int row = gr + r;
        if (!isv) {
          if (isq) val *= QSCALE;
          QK[(size_t)row * 1536 + gc] = f2bf(val);
        } else {
          const int bb = row >> 10, tt = row & 1023;
          // sigma: bit2 <- tt.bit4, bits4..3 <- tt.bits3..2
          const int tt2 = (tt & ~0x1C) | (((tt >> 4) & 1) << 2) |
                          (((tt >> 2) & 3) << 3);
          VT[(((size_t)(bb * 8 + hh)) * 96 + dd) * 1024 + tt2] = f2bf(val);
        }
      }
    }
  }
}

// ---------------------------------------------------------------------------
// Generic GEMM (proj): C[m][n] = sum_k A[m][k] W[n][k] + bias[n], f32 out.
// K = 768 fixed.
// ---------------------------------------------------------------------------
__global__ __launch_bounds__(64, 2) void gemm_proj(
    const ushort_t* __restrict__ A,   // M x 768 bf16
    const ushort_t* __restrict__ W,   // N x 768 bf16
    const float* __restrict__ bias,   // N f32
    float* __restrict__ C,            // M x N f32
    int M, int N)
{
  SGEMM_BODY(A, W);

#pragma unroll
  for (int tn = 0; tn < 4; ++tn) {
    const int gc = n0 + tn * 16 + l15;
    const float bv = bias[gc];
#pragma unroll
    for (int tm = 0; tm < 4; ++tm) {
      const int gr = m0 + tm * 16 + quad * 4;
#pragma unroll
      for (int r = 0; r < 4; ++r)
        C[(size_t)(gr + r) * N + gc] = acc[tm][tn][r] + bv;
    }
  }
}

// ---------------------------------------------------------------------------
// Fused causal flash attention, swapped-QK^T form, zero-sync streaming.
// Grid (64, 64): block = 1 wave = 16 q-rows of one (b,h). Each wave loops
// k-tiles up to ITS OWN causal bound and exits. K fragments stream from QK,
// V fragments stream from the sigma-permuted VT (both L2-resident).
// s[t] row=quad*4+j = key t*16+quad*4+j, col=l15 = q-row. Softmax per-row is
// lane-local (+2 shfl_xor). PV A-frag assembles in-lane via cvt_pk pairs.
// ---------------------------------------------------------------------------
__global__ __launch_bounds__(64, 3) void attn_fused(
    const ushort_t* __restrict__ QK,   // (B*T) x 1536 bf16  [q*scale | k]
    const ushort_t* __restrict__ VT,   // (64 bh) x 96 x 1024 bf16 (perm cols)
    ushort_t* __restrict__ y)          // (B*T) x 768 bf16
{
  const int tid  = threadIdx.x;
  const int l15  = tid & 15;
  const int quad = tid >> 4;
  const int bh = blockIdx.y;
  const int b = bh >> 3;
  const int h = bh & 7;
  const int qoff = h * 96;

  const int q0w = blockIdx.x * 16;     // wave's first q row
  const int rq = q0w + l15;            // this lane's q row
  const int kendw = q0w + 16;          // own causal bound

  const size_t rowbase = (size_t)b * 1024;
  const ushort_t* vtb = VT + (size_t)bh * 96 * 1024;
  const ushort_t* kbase = QK + rowbase * 1536 + 768 + qoff;

  // Q fragments (used as B operand), K=96 in 3 chunks of 32
  short8 qf[3];
#pragma unroll
  for (int c = 0; c < 3; ++c)
    qf[c] = *(const short8*)(QK + (rowbase + q0w + l15) * 1536 + qoff +
                             c * 32 + quad * 8);

  float m_i = NEG_BIG;   // running max for row l15 (exp2 domain)
  float l_i = 0.f;       // running denom for row l15
  floatx4 O[6] = {};

  for (int k0 = 0; k0 < kendw; k0 += 64) {
    // QK^T swapped: s[t] = K_tile(t) * Q  -> rows=keys, cols=q
    floatx4 s[4] = {};
    short8 kf[4][3];
#pragma unroll
    for (int t = 0; t < 4; ++t)
#pragma unroll
      for (int c = 0; c < 3; ++c)
        kf[t][c] = *(const short8*)
            (kbase + (size_t)(k0 + t * 16 + l15) * 1536 + c * 32 + quad * 8);
    __builtin_amdgcn_s_setprio(1);
#pragma unroll
    for (int t = 0; t < 4; ++t)
#pragma unroll
      for (int c = 0; c < 3; ++c)
        s[t] = MFMA16(kf[t][c], qf[c], s[t]);
    __builtin_amdgcn_s_setprio(0);

    // scores for row rq: key = k0 + t*16 + quad*4 + j
    float p[4][4];
    if (k0 + 64 <= q0w) {            // fully unmasked tile (fast path)
#pragma unroll
      for (int t = 0; t < 4; ++t)
#pragma unroll
        for (int j = 0; j < 4; ++j) p[t][j] = s[t][j];
    } else {                          // diagonal tile: causal mask
      const int kq = k0 + quad * 4;
#pragma unroll
      for (int t = 0; t < 4; ++t)
#pragma unroll
        for (int j = 0; j < 4; ++j)
          p[t][j] = (kq + t * 16 + j <= rq) ? s[t][j] : NEG_BIG;
    }
    // row max: in-lane tree (16) + cross-quad
    float m0v = fmaxf(fmaxf(p[0][0], p[0][1]), fmaxf(p[0][2], p[0][3]));
    float m1v = fmaxf(fmaxf(p[1][0], p[1][1]), fmaxf(p[1][2], p[1][3]));
    float m2v = fmaxf(fmaxf(p[2][0], p[2][1]), fmaxf(p[2][2], p[2][3]));
    float m3v = fmaxf(fmaxf(p[3][0], p[3][1]), fmaxf(p[3][2], p[3][3]));
    float mt = fmaxf(fmaxf(m0v, m1v), fmaxf(m2v, m3v));
    mt = fmaxf(mt, __shfl_xor(mt, 16));
    mt = fmaxf(mt, __shfl_xor(mt, 32));
    // defer-max: only rescale when max grew by > 8 (exp2 headroom 2^8)
    if (!__all(mt - m_i <= 8.0f)) {
      const float mn = fmaxf(m_i, mt);
      const float al = __builtin_amdgcn_exp2f(m_i - mn);
      m_i = mn;
      l_i *= al;
#pragma unroll
      for (int j = 0; j < 4; ++j) {
        const float alr = __shfl(al, quad * 4 + j);  // al of O-row quad*4+j
#pragma unroll
        for (int f = 0; f < 6; ++f) O[f][j] *= alr;
      }
    }
    float rs = 0.f;
#pragma unroll
    for (int t = 0; t < 4; ++t)
#pragma unroll
      for (int j = 0; j < 4; ++j) {
        p[t][j] = __builtin_amdgcn_exp2f(p[t][j] - m_i);
        rs += p[t][j];
      }
    rs += __shfl_xor(rs, 16);
    rs += __shfl_xor(rs, 32);
    l_i += rs;
    // pack P to bf16 A-frags entirely in-lane (keys pre-permuted into VT)
    union { short8 s8; unsigned int u[4]; } pf0, pf1;
    pf0.u[0] = packbf2(p[0][0], p[0][1]);
    pf0.u[1] = packbf2(p[0][2], p[0][3]);
    pf0.u[2] = packbf2(p[1][0], p[1][1]);
    pf0.u[3] = packbf2(p[1][2], p[1][3]);
    pf1.u[0] = packbf2(p[2][0], p[2][1]);
    pf1.u[1] = packbf2(p[2][2], p[2][3]);
    pf1.u[2] = packbf2(p[3][0], p[3][1]);
    pf1.u[3] = packbf2(p[3][2], p[3][3]);

    // V fragments straight from permuted VT (columns k0..k0+63)
    short8 vf[6][2];
#pragma unroll
    for (int f = 0; f < 6; ++f)
#pragma unroll
      for (int u = 0; u < 2; ++u)
        vf[f][u] = *(const short8*)
            (vtb + (size_t)(f * 16 + l15) * 1024 + k0 + u * 32 + quad * 8);
    __builtin_amdgcn_s_setprio(1);
#pragma unroll
    for (int f = 0; f < 6; ++f) {
      O[f] = MFMA16(pf0.s8, vf[f][0], O[f]);
      O[f] = MFMA16(pf1.s8, vf[f][1], O[f]);
    }
    __builtin_amdgcn_s_setprio(0);
  }

  // epilogue: O rows are quad*4+j; softmax denom lives in lane (row)
  float inv[4];
#pragma unroll
  for (int j = 0; j < 4; ++j) {
    const float lj = __shfl(l_i, quad * 4 + j);
    inv[j] = 1.0f / fmaxf(lj, 1e-20f);
  }
#pragma unroll
  for (int j = 0; j < 4; ++j) {
    const size_t row = rowbase + q0w + quad * 4 + j;
#pragma unroll
    for (int f = 0; f < 6; ++f)
      y[row * 768 + qoff + f * 16 + l15] = f2bf(O[f][j] * inv[j]);
  }
}

// ---------------------------------------------------------------------------
extern "C" void kernel_launch(void* const* d_in, const int* in_sizes, int n_in,
                              void* d_out, int out_size, void* d_ws, size_t ws_size,
                              hipStream_t stream)
{
  const float* x_f  = (const float*)d_in[0];
  const float* wa_f = (const float*)d_in[1];
  const float* ba_f = (const float*)d_in[2];
  const float* wp_f = (const float*)d_in[3];
  const float* bp_f = (const float*)d_in[4];
  float* out = (float*)d_out;

  ushort_t* xb  = (ushort_t*)d_ws;                    // 8192 x  768
  ushort_t* wab = xb  + (size_t)8192 * 768;           // 2304 x  768
  ushort_t* wpb = wab + (size_t)2304 * 768;           //  768 x  768
  ushort_t* QK  = wpb + (size_t)768 * 768;            // 8192 x 1536
  ushort_t* VT  = QK  + (size_t)8192 * 1536;          // 64 x 96 x 1024
  ushort_t* yw  = VT  + (size_t)8192 * 768;           // 8192 x  768

  // (8192*768 + 2304*768 + 768*768)/4 = 2162688 = 8448 * 256
  cvt3<<<8448, 256, 0, stream>>>(x_f, wa_f, wp_f, xb, wab, wpb);

  gemm_qkv<<<dim3(128, 36), 64, 0, stream>>>(xb, wab, ba_f, QK, VT);
  attn_fused<<<dim3(64, 64), 64, 0, stream>>>(QK, VT, yw);
  gemm_proj<<<dim3(128, 12), 64, 0, stream>>>(yw, wpb, bp_f, out,
                                              8192, 768);
}

// Round 7
// 206.008 us; speedup vs baseline: 2.0079x; 2.0079x over previous
//
#include <hip/hip_runtime.h>
#include <hip/hip_bf16.h>
#include <stdint.h>

// GPT causal self-attention block. B=8, T=1024, C=768, H=8, D=96. f32 I/O.
// bf16 MFMA pipeline with fp32 accumulation. Causal mask input ignored.
//
// R6: revert GEMMs to the verified R4 structure (zero-sync streaming of R5
// destroyed L2 locality). Attention reworked: one 64-row q-chunk per block
// (4 waves x 16 rows), kend = (chunk+1)*64 -> every wave's causal bound ==
// block loop bound (no idle wave-steps; 2.9x less K/V staging than the
// paired-chunk scheme). Bijective XCD swizzle groups 8 consecutive bh per
// XCD -> per-XCD K/V working set 3 MB, L2-resident.

typedef unsigned short ushort_t;
typedef __attribute__((ext_vector_type(8))) short short8;     // 8 bf16 = 4 VGPRs
typedef __attribute__((ext_vector_type(4))) float floatx4;    // MFMA C/D frag
typedef __attribute__((ext_vector_type(4))) unsigned short ushort4v;

#define MFMA16(a, b, c) __builtin_amdgcn_mfma_f32_16x16x32_bf16(a, b, c, 0, 0, 0)
#define NEG_BIG (-1e30f)

__device__ __forceinline__ unsigned short f2bf(float f) {
  union { float f; unsigned int u; } v; v.f = f;
  unsigned int r = (v.u + 0x7FFFu + ((v.u >> 16) & 1u)) >> 16;  // RNE
  return (unsigned short)r;
}

__device__ __forceinline__ unsigned int packbf2(float a, float b) {
  // low 16 = bf16(a), high 16 = bf16(b)  (v_cvt_pk_bf16_f32)
  union { __hip_bfloat162 h; unsigned int u; } cv;
  cv.h = __float22bfloat162_rn(make_float2(a, b));
  return cv.u;
}

#define GLOAD16(src, dst)                                              \
  __builtin_amdgcn_global_load_lds(                                    \
      (const __attribute__((address_space(1))) void*)(src),            \
      (__attribute__((address_space(3))) void*)(dst), 16, 0, 0)

// counted wait + raw barrier (no vmcnt(0) auto-drain like __syncthreads)
#define WAITBAR(VM)                                                    \
  do {                                                                 \
    asm volatile("s_waitcnt vmcnt(" #VM ")" ::: "memory");             \
    __builtin_amdgcn_s_barrier();                                      \
  } while (0)

#define WAITBAR_LGKM(VM)                                               \
  do {                                                                 \
    asm volatile("s_waitcnt vmcnt(" #VM ") lgkmcnt(0)" ::: "memory");  \
    __builtin_amdgcn_s_barrier();                                      \
  } while (0)

// ---------------------------------------------------------------------------
// Fused f32->bf16 conversion for x, Wqkv, Wproj in one launch.
// ---------------------------------------------------------------------------
__global__ __launch_bounds__(256) void cvt3(
    const float* __restrict__ x, const float* __restrict__ wa,
    const float* __restrict__ wp, ushort_t* __restrict__ xb,
    ushort_t* __restrict__ wab, ushort_t* __restrict__ wpb)
{
  const int n1 = (8192 * 768) / 4, n2 = (2304 * 768) / 4;
  int i = blockIdx.x * 256 + threadIdx.x;
  const float* in; ushort_t* out;
  if (i < n1)            { in = x;  out = xb; }
  else if (i < n1 + n2)  { in = wa; out = wab; i -= n1; }
  else                   { in = wp; out = wpb; i -= (n1 + n2); }
  float4 v = *(const float4*)(in + (size_t)i * 4);
  ushort4v o;
  o.x = f2bf(v.x); o.y = f2bf(v.y); o.z = f2bf(v.z); o.w = f2bf(v.w);
  *(ushort4v*)(out + (size_t)i * 4) = o;
}

// ---------------------------------------------------------------------------
// Shared GEMM machinery: 128x128 tile, BK=32, 4 waves 2x2, 3 SEPARATE LDS
// buffers, 2-deep prefetch with counted vmcnt(4). K = 768 (24 steps), fully
// static buffer rotation.
// ---------------------------------------------------------------------------
#define GSTAGE(LA, LB, OFF)                                            \
  do {                                                                 \
    GLOAD16(gA + (OFF), &LA[wid * 512]);                               \
    GLOAD16(gA + (OFF) + (size_t)64 * 768, &LA[wid * 512 + 64 * 32]);  \
    GLOAD16(gB + (OFF), &LB[wid * 512]);                               \
    GLOAD16(gB + (OFF) + (size_t)64 * 768, &LB[wid * 512 + 64 * 32]);  \
  } while (0)

#define GCOMP(LA, LB)                                                  \
  do {                                                                 \
    short8 af[4], bf[4];                                               \
    _Pragma("unroll")                                                  \
    for (int t_ = 0; t_ < 4; ++t_) {                                   \
      af[t_] = *(const short8*)&LA[(wm + t_ * 16 + l15) * 32 + sw];    \
      bf[t_] = *(const short8*)&LB[(wn + t_ * 16 + l15) * 32 + sw];    \
    }                                                                  \
    __builtin_amdgcn_s_setprio(1);                                     \
    _Pragma("unroll")                                                  \
    for (int tm = 0; tm < 4; ++tm)                                     \
      _Pragma("unroll")                                                \
      for (int tn = 0; tn < 4; ++tn)                                   \
        acc[tm][tn] = MFMA16(af[tm], bf[tn], acc[tm][tn]);             \
    __builtin_amdgcn_s_setprio(0);                                     \
  } while (0)

// three steps t, t+1, t+2 (cur buffers 0,1,2; stage targets 2,0,1)
#define GK3(T)                                                         \
  WAITBAR(4); GSTAGE(As2, Bs2, ((T) + 2) * 32); GCOMP(As0, Bs0);       \
  WAITBAR(4); GSTAGE(As0, Bs0, ((T) + 3) * 32); GCOMP(As1, Bs1);       \
  WAITBAR(4); GSTAGE(As1, Bs1, ((T) + 4) * 32); GCOMP(As2, Bs2);

#define GEMM_KLOOP                                                     \
  GSTAGE(As0, Bs0, 0); GSTAGE(As1, Bs1, 32);                           \
  GK3(0) GK3(3) GK3(6) GK3(9) GK3(12) GK3(15) GK3(18)                  \
  WAITBAR(4); GSTAGE(As2, Bs2, 23 * 32); GCOMP(As0, Bs0);              \
  WAITBAR(4); GCOMP(As1, Bs1);                                         \
  WAITBAR(0); GCOMP(As2, Bs2);

#define GEMM_DECLS                                                     \
  __shared__ ushort_t As0[128 * 32], As1[128 * 32], As2[128 * 32];     \
  __shared__ ushort_t Bs0[128 * 32], Bs1[128 * 32], Bs2[128 * 32];     \
  const int tid  = threadIdx.x;                                        \
  const int lane = tid & 63;                                           \
  const int l15  = lane & 15;                                          \
  const int quad = lane >> 4;                                          \
  const int wid  = tid >> 6;                                           \
  const int m0 = blockIdx.x * 128;                                     \
  const int n0 = blockIdx.y * 128;                                     \
  const int wm = (wid >> 1) * 64;                                      \
  const int wn = (wid & 1) * 64;                                       \
  const int srow = tid >> 2;                                           \
  const int scol = (((tid & 3) ^ ((srow ^ (srow >> 2)) & 3))) * 8;     \
  const int sw = (quad ^ ((l15 ^ (l15 >> 2)) & 3)) * 8;                \
  floatx4 acc[4][4] = {};

// ---------------------------------------------------------------------------
// QKV GEMM: qkv = x @ Wqkv^T + b. Q columns pre-scaled by (1/sqrt(96))*log2e.
// Writes q,k into QK (row stride 1536) and v TRANSPOSED into VT[b][h][d][T]
// with time index sigma-permuted within each 64-block (attention needs no
// cross-lane P exchange).
// ---------------------------------------------------------------------------
__global__ __launch_bounds__(256) void gemm_qkv(
    const ushort_t* __restrict__ A,   // 8192 x 768 bf16 (x)
    const ushort_t* __restrict__ W,   // 2304 x 768 bf16
    const float* __restrict__ bias,   // 2304 f32
    ushort_t* __restrict__ QK,        // 8192 x 1536 bf16
    ushort_t* __restrict__ VT)        // (64 bh) x 96 x 1024 bf16 (perm cols)
{
  GEMM_DECLS;

  const ushort_t* gA = A + (size_t)(m0 + srow) * 768 + scol;
  const ushort_t* gB = W + (size_t)(n0 + srow) * 768 + scol;

  GEMM_KLOOP;

  const float QSCALE = 0.10206207261596577f * 1.4426950408889634f;

#pragma unroll
  for (int tn = 0; tn < 4; ++tn) {
    const int gc = n0 + wn + tn * 16 + l15;
    const float bv = bias[gc];
    const bool isv = (gc >= 1536);          // whole 16-col tile same side
    const bool isq = (gc < 768);
    const int hh = (gc - 1536) / 96, dd = (gc - 1536) % 96;
#pragma unroll
    for (int tm = 0; tm < 4; ++tm) {
      const int gr = m0 + wm + tm * 16 + quad * 4;
#pragma unroll
      for (int r = 0; r < 4; ++r) {
        float val = acc[tm][tn][r] + bv;
        const int row = gr + r;
        if (!isv) {
          if (isq) val *= QSCALE;
          QK[(size_t)row * 1536 + gc] = f2bf(val);
        } else {
          const int bb = row >> 10, tt = row & 1023;
          // sigma: bit2 <- tt.bit4, bits4..3 <- tt.bits3..2
          const int tt2 = (tt & ~0x1C) | (((tt >> 4) & 1) << 2) |
                          (((tt >> 2) & 3) << 3);
          VT[(((size_t)(bb * 8 + hh)) * 96 + dd) * 1024 + tt2] = f2bf(val);
        }
      }
    }
  }
}

// ---------------------------------------------------------------------------
// Generic GEMM (proj): C[m][n] = sum_k A[m][k] W[n][k] + bias[n], f32 out.
// K = 768 fixed. Same counted pipeline.
// ---------------------------------------------------------------------------
__global__ __launch_bounds__(256) void gemm_proj(
    const ushort_t* __restrict__ A,   // M x 768 bf16
    const ushort_t* __restrict__ W,   // N x 768 bf16
    const float* __restrict__ bias,   // N f32
    float* __restrict__ C,            // M x N f32
    int M, int N)
{
  GEMM_DECLS;

  const ushort_t* gA = A + (size_t)(m0 + srow) * 768 + scol;
  const ushort_t* gB = W + (size_t)(n0 + srow) * 768 + scol;

  GEMM_KLOOP;

#pragma unroll
  for (int tn = 0; tn < 4; ++tn) {
    const int gc = n0 + wn + tn * 16 + l15;
    const float bv = bias[gc];
#pragma unroll
    for (int tm = 0; tm < 4; ++tm) {
      const int gr = m0 + wm + tm * 16 + quad * 4;
#pragma unroll
      for (int r = 0; r < 4; ++r)
        C[(size_t)(gr + r) * N + gc] = acc[tm][tn][r] + bv;
    }
  }
}

// ---------------------------------------------------------------------------
// Fused causal flash attention, swapped-QK^T form, counted-vmcnt pipeline.
// R6 mapping: grid (16, 64); block = one 64-row q-chunk of one (b,h).
// chunk/bh derived from an XCD-swizzled linear id (8 consecutive bh per
// XCD -> K/V L2-resident). Waves own rows chunk*64 + wid*16; kend =
// (chunk+1)*64 so every wave is active in every iteration (no idle slots).
// ---------------------------------------------------------------------------
#define ATTN_COMPUTE(KS, VTC, K0)                                      \
  do {                                                                 \
    floatx4 s[4] = {};                                                 \
    __builtin_amdgcn_s_setprio(1);                                     \
    _Pragma("unroll")                                                  \
    for (int t = 0; t < 4; ++t) {                                      \
      _Pragma("unroll")                                                \
      for (int c = 0; c < 3; ++c) {                                    \
        short8 kf = *(const short8*)                                   \
            &KS[(t * 16 + l15) * 96 + c * 32 + quad * 8];              \
        s[t] = MFMA16(kf, qf[c], s[t]);                                \
      }                                                                \
    }                                                                  \
    __builtin_amdgcn_s_setprio(0);                                     \
    float p[4][4];                                                     \
    if ((K0) + 64 <= q0w) {                                            \
      _Pragma("unroll")                                                \
      for (int t = 0; t < 4; ++t)                                      \
        _Pragma("unroll")                                              \
        for (int j = 0; j < 4; ++j) p[t][j] = s[t][j];                 \
    } else {                                                           \
      const int kq = (K0) + quad * 4;                                  \
      _Pragma("unroll")                                                \
      for (int t = 0; t < 4; ++t)                                      \
        _Pragma("unroll")                                              \
        for (int j = 0; j < 4; ++j)                                    \
          p[t][j] = (kq + t * 16 + j <= rq) ? s[t][j] : NEG_BIG;       \
    }                                                                  \
    float m0v = fmaxf(fmaxf(p[0][0], p[0][1]), fmaxf(p[0][2], p[0][3]));\
    float m1v = fmaxf(fmaxf(p[1][0], p[1][1]), fmaxf(p[1][2], p[1][3]));\
    float m2v = fmaxf(fmaxf(p[2][0], p[2][1]), fmaxf(p[2][2], p[2][3]));\
    float m3v = fmaxf(fmaxf(p[3][0], p[3][1]), fmaxf(p[3][2], p[3][3]));\
    float mt = fmaxf(fmaxf(m0v, m1v), fmaxf(m2v, m3v));                \
    mt = fmaxf(mt, __shfl_xor(mt, 16));                                \
    mt = fmaxf(mt, __shfl_xor(mt, 32));                                \
    if (!__all(mt - m_i <= 8.0f)) {                                    \
      const float mn = fmaxf(m_i, mt);                                 \
      const float al = __builtin_amdgcn_exp2f(m_i - mn);               \
      m_i = mn;                                                        \
      l_i *= al;                                                       \
      _Pragma("unroll")                                                \
      for (int j = 0; j < 4; ++j) {                                    \
        const float alr = __shfl(al, quad * 4 + j);                    \
        _Pragma("unroll")                                              \
        for (int f = 0; f < 6; ++f) O[f][j] *= alr;                    \
      }                                                                \
    }                                                                  \
    float rs = 0.f;                                                    \
    _Pragma("unroll")                                                  \
    for (int t = 0; t < 4; ++t)                                        \
      _Pragma("unroll")                                                \
      for (int j = 0; j < 4; ++j) {                                    \
        p[t][j] = __builtin_amdgcn_exp2f(p[t][j] - m_i);               \
        rs += p[t][j];                                                 \
      }                                                                \
    rs += __shfl_xor(rs, 16);                                          \
    rs += __shfl_xor(rs, 32);                                          \
    l_i += rs;                                                         \
    union { short8 s8; unsigned int u[4]; } pf0, pf1;                  \
    pf0.u[0] = packbf2(p[0][0], p[0][1]);                              \
    pf0.u[1] = packbf2(p[0][2], p[0][3]);                              \
    pf0.u[2] = packbf2(p[1][0], p[1][1]);                              \
    pf0.u[3] = packbf2(p[1][2], p[1][3]);                              \
    pf1.u[0] = packbf2(p[2][0], p[2][1]);                              \
    pf1.u[1] = packbf2(p[2][2], p[2][3]);                              \
    pf1.u[2] = packbf2(p[3][0], p[3][1]);                              \
    pf1.u[3] = packbf2(p[3][2], p[3][3]);                              \
    __builtin_amdgcn_s_setprio(1);                                     \
    _Pragma("unroll")                                                  \
    for (int f = 0; f < 6; ++f) {                                      \
      short8 vf0 = *(const short8*)&VTC[(f * 16 + l15) * 72 + quad * 8];\
      O[f] = MFMA16(pf0.s8, vf0, O[f]);                                \
      short8 vf1 = *(const short8*)                                    \
          &VTC[(f * 16 + l15) * 72 + 32 + quad * 8];                   \
      O[f] = MFMA16(pf1.s8, vf1, O[f]);                                \
    }                                                                  \
    __builtin_amdgcn_s_setprio(0);                                     \
  } while (0)

// one pipelined iteration (never the last): wait, stage K(t+1) into KSN,
// compute(t) from KS/VTC, write V(t+1) into VTN, load V(t+2) regs.
#define AITER(KS, VTC, KSN, VTN, K0)                                   \
  do {                                                                 \
    const int k0_ = (K0);                                              \
    const int nk_ = k0_ + 64;                                          \
    WAITBAR_LGKM(3);                                                   \
    _Pragma("unroll")                                                  \
    for (int i = 0; i < 3; ++i) {                                      \
      const int e = ke0 + i * 512;                                     \
      const int kr = e / 96, kc = e % 96;                              \
      GLOAD16(QK + (rowbase + nk_ + kr) * 1536 + 768 + qoff + kc,      \
              &KSN[wid * 1536 + i * 512]);                             \
    }                                                                  \
    ATTN_COMPUTE(KS, VTC, k0_);                                        \
    _Pragma("unroll")                                                  \
    for (int g = 0; g < 3; ++g)                                        \
      *(short8*)&VTN[(g * 32 + vd) * 72 + vkc] = vreg[g];              \
    if (nk_ + 64 < kend) {                                             \
      _Pragma("unroll")                                                \
      for (int g = 0; g < 3; ++g)                                      \
        vreg[g] = *(const short8*)                                     \
            (vtb + (size_t)(g * 32 + vd) * 1024 + nk_ + 64 + vkc);     \
    }                                                                  \
  } while (0)

#define AITER_LAST(KS, VTC, K0)                                        \
  do {                                                                 \
    WAITBAR_LGKM(0);                                                   \
    ATTN_COMPUTE(KS, VTC, (K0));                                       \
  } while (0)

__global__ __launch_bounds__(256) void attn_fused(
    const ushort_t* __restrict__ QK,   // (B*T) x 1536 bf16  [q*scale | k]
    const ushort_t* __restrict__ VT,   // (64 bh) x 96 x 1024 bf16 (perm cols)
    ushort_t* __restrict__ y)          // (B*T) x 768 bf16
{
  __shared__ ushort_t Ks0[64 * 96], Ks1[64 * 96];
  __shared__ ushort_t Vt0[96 * 72], Vt1[96 * 72];

  const int tid  = threadIdx.x;
  const int lane = tid & 63;
  const int l15  = lane & 15;
  const int quad = lane >> 4;
  const int wid  = tid >> 6;

  // XCD-swizzled work assignment: linear id -> (chunk, bh); 1024 = 128 x 8,
  // XCD c (= lin % 8) gets bh in [c*8, c*8+8) for all 16 chunks.
  const int lin = blockIdx.x + (blockIdx.y << 4);
  const int swz = ((lin & 7) << 7) + (lin >> 3);
  const int chunk = swz & 15;          // 0..15 (q rows chunk*64 .. +63)
  const int bh = swz >> 4;             // 0..63
  const int b = bh >> 3;
  const int h = bh & 7;
  const int qoff = h * 96;

  const int q0w = chunk * 64 + wid * 16;   // wave's first q row
  const int kend = chunk * 64 + 64;        // block loop bound == causal bound
  const int rq = q0w + l15;                // this lane's q row

  const size_t rowbase = (size_t)b * 1024;
  const ushort_t* vtb = VT + (size_t)bh * 96 * 1024;

  // per-thread staging coords
  const int ke0 = wid * 1536 + lane * 8;           // K-stage element base
  const int vd  = (tid >> 3);                      // V-stage row within group
  const int vkc = (tid & 7) * 8;                   // V-stage col

  // Q fragments (used as B operand), K=96 in 3 chunks of 32
  short8 qf[3];
#pragma unroll
  for (int c = 0; c < 3; ++c)
    qf[c] = *(const short8*)(QK + (rowbase + q0w + l15) * 1536 + qoff +
                             c * 32 + quad * 8);

  float m_i = NEG_BIG;   // running max for row l15 (exp2 domain)
  float l_i = 0.f;       // running denom for row l15
  floatx4 O[6] = {};

  short8 vreg[3];

  // prologue: V(0) regs FIRST, K(0) gloads, write V(0), issue V(1) regs.
#pragma unroll
  for (int g = 0; g < 3; ++g)
    vreg[g] = *(const short8*)(vtb + (size_t)(g * 32 + vd) * 1024 + vkc);
#pragma unroll
  for (int i = 0; i < 3; ++i) {
    const int e = ke0 + i * 512;
    const int kr = e / 96, kc = e % 96;
    GLOAD16(QK + (rowbase + kr) * 1536 + 768 + qoff + kc,
            &Ks0[wid * 1536 + i * 512]);
  }
#pragma unroll
  for (int g = 0; g < 3; ++g)
    *(short8*)&Vt0[(g * 32 + vd) * 72 + vkc] = vreg[g];
#pragma unroll
  for (int g = 0; g < 3; ++g)
    vreg[g] = *(const short8*)(vtb + (size_t)(g * 32 + vd) * 1024 + 64 + vkc);

  // main loop: pairs of tiles with static buffers; 1-or-2 iteration tail.
  int k0 = 0;
  while (k0 + 128 < kend) {
    AITER(Ks0, Vt0, Ks1, Vt1, k0);
    AITER(Ks1, Vt1, Ks0, Vt0, k0 + 64);
    k0 += 128;
  }
  if (k0 + 64 < kend) {
    AITER(Ks0, Vt0, Ks1, Vt1, k0);
    AITER_LAST(Ks1, Vt1, k0 + 64);
  } else {
    AITER_LAST(Ks0, Vt0, k0);
  }

  // epilogue: O rows are quad*4+j; softmax denom lives in lane (row)
  float inv[4];
#pragma unroll
  for (int j = 0; j < 4; ++j) {
    const float lj = __shfl(l_i, quad * 4 + j);
    inv[j] = 1.0f / fmaxf(lj, 1e-20f);
  }
#pragma unroll
  for (int j = 0; j < 4; ++j) {
    const size_t row = rowbase + q0w + quad * 4 + j;
#pragma unroll
    for (int f = 0; f < 6; ++f)
      y[row * 768 + qoff + f * 16 + l15] = f2bf(O[f][j] * inv[j]);
  }
}

// ---------------------------------------------------------------------------
extern "C" void kernel_launch(void* const* d_in, const int* in_sizes, int n_in,
                              void* d_out, int out_size, void* d_ws, size_t ws_size,
                              hipStream_t stream)
{
  const float* x_f  = (const float*)d_in[0];
  const float* wa_f = (const float*)d_in[1];
  const float* ba_f = (const float*)d_in[2];
  const float* wp_f = (const float*)d_in[3];
  const float* bp_f = (const float*)d_in[4];
  float* out = (float*)d_out;

  ushort_t* xb  = (ushort_t*)d_ws;                    // 8192 x  768
  ushort_t* wab = xb  + (size_t)8192 * 768;           // 2304 x  768
  ushort_t* wpb = wab + (size_t)2304 * 768;           //  768 x  768
  ushort_t* QK  = wpb + (size_t)768 * 768;            // 8192 x 1536
  ushort_t* VT  = QK  + (size_t)8192 * 1536;          // 64 x 96 x 1024
  ushort_t* yw  = VT  + (size_t)8192 * 768;           // 8192 x  768

  // (8192*768 + 2304*768 + 768*768)/4 = 2162688 = 8448 * 256
  cvt3<<<8448, 256, 0, stream>>>(x_f, wa_f, wp_f, xb, wab, wpb);

  gemm_qkv<<<dim3(64, 18), 256, 0, stream>>>(xb, wab, ba_f, QK, VT);
  attn_fused<<<dim3(16, 64), 256, 0, stream>>>(QK, VT, yw);
  gemm_proj<<<dim3(64, 6), 256, 0, stream>>>(yw, wpb, bp_f, out,
                                             8192, 768);
}

// Round 8
// 204.707 us; speedup vs baseline: 2.0207x; 1.0064x over previous
//
#include <hip/hip_runtime.h>
#include <hip/hip_bf16.h>
#include <stdint.h>

// GPT causal self-attention block. B=8, T=1024, C=768, H=8, D=96. f32 I/O.
// bf16 MFMA pipeline with fp32 accumulation. Causal mask input ignored.
//
// R7: GEMM occupancy play. 2 LDS buffers (32 KB -> 5 blocks/CU) with the
// counted-vmcnt kept. Two-barrier step: {vmcnt(4); bar; ds_reads;
// lgkmcnt(0); bar; stage(t+2) into the just-read buffer; MFMA}. Loads keep
// a full step in flight; resident-block stagger fills barrier slack.
// attn unchanged from R6 (chunk-per-block + XCD swizzle, improved).

typedef unsigned short ushort_t;
typedef __attribute__((ext_vector_type(8))) short short8;     // 8 bf16 = 4 VGPRs
typedef __attribute__((ext_vector_type(4))) float floatx4;    // MFMA C/D frag
typedef __attribute__((ext_vector_type(4))) unsigned short ushort4v;

#define MFMA16(a, b, c) __builtin_amdgcn_mfma_f32_16x16x32_bf16(a, b, c, 0, 0, 0)
#define NEG_BIG (-1e30f)

__device__ __forceinline__ unsigned short f2bf(float f) {
  union { float f; unsigned int u; } v; v.f = f;
  unsigned int r = (v.u + 0x7FFFu + ((v.u >> 16) & 1u)) >> 16;  // RNE
  return (unsigned short)r;
}

__device__ __forceinline__ unsigned int packbf2(float a, float b) {
  // low 16 = bf16(a), high 16 = bf16(b)  (v_cvt_pk_bf16_f32)
  union { __hip_bfloat162 h; unsigned int u; } cv;
  cv.h = __float22bfloat162_rn(make_float2(a, b));
  return cv.u;
}

#define GLOAD16(src, dst)                                              \
  __builtin_amdgcn_global_load_lds(                                    \
      (const __attribute__((address_space(1))) void*)(src),            \
      (__attribute__((address_space(3))) void*)(dst), 16, 0, 0)

// counted wait + raw barrier (no vmcnt(0) auto-drain like __syncthreads)
#define WAITBAR(VM)                                                    \
  do {                                                                 \
    asm volatile("s_waitcnt vmcnt(" #VM ")" ::: "memory");             \
    __builtin_amdgcn_s_barrier();                                      \
  } while (0)

#define WAITBAR_LGKM(VM)                                               \
  do {                                                                 \
    asm volatile("s_waitcnt vmcnt(" #VM ") lgkmcnt(0)" ::: "memory");  \
    __builtin_amdgcn_s_barrier();                                      \
  } while (0)

// ---------------------------------------------------------------------------
// Fused f32->bf16 conversion for x, Wqkv, Wproj in one launch.
// ---------------------------------------------------------------------------
__global__ __launch_bounds__(256) void cvt3(
    const float* __restrict__ x, const float* __restrict__ wa,
    const float* __restrict__ wp, ushort_t* __restrict__ xb,
    ushort_t* __restrict__ wab, ushort_t* __restrict__ wpb)
{
  const int n1 = (8192 * 768) / 4, n2 = (2304 * 768) / 4;
  int i = blockIdx.x * 256 + threadIdx.x;
  const float* in; ushort_t* out;
  if (i < n1)            { in = x;  out = xb; }
  else if (i < n1 + n2)  { in = wa; out = wab; i -= n1; }
  else                   { in = wp; out = wpb; i -= (n1 + n2); }
  float4 v = *(const float4*)(in + (size_t)i * 4);
  ushort4v o;
  o.x = f2bf(v.x); o.y = f2bf(v.y); o.z = f2bf(v.z); o.w = f2bf(v.w);
  *(ushort4v*)(out + (size_t)i * 4) = o;
}

// ---------------------------------------------------------------------------
// GEMM machinery: 128x128 tile, BK=32, 4 waves 2x2, 2 LDS buffers (32 KB ->
// 5 blocks/CU), counted vmcnt(4). K = 768 (24 steps), static buffer chain.
// Step t: {vmcnt(4); bar; ds_read frags; lgkmcnt(0); bar; stage tile t+2
// into this same buffer; MFMA}. Mid-step barrier makes read-then-overwrite
// safe; loads get a full step in flight; drains to 0 only at the tail.
// ---------------------------------------------------------------------------
#define GSTAGE(LA, LB, OFF)                                            \
  do {                                                                 \
    GLOAD16(gA + (OFF), &LA[wid * 512]);                               \
    GLOAD16(gA + (OFF) + (size_t)64 * 768, &LA[wid * 512 + 64 * 32]);  \
    GLOAD16(gB + (OFF), &LB[wid * 512]);                               \
    GLOAD16(gB + (OFF) + (size_t)64 * 768, &LB[wid * 512 + 64 * 32]);  \
  } while (0)

#define GSTEP(LA, LB, OFF, STG, VM)                                    \
  do {                                                                 \
    asm volatile("s_waitcnt vmcnt(" #VM ")" ::: "memory");             \
    __builtin_amdgcn_s_barrier();                                      \
    short8 af[4], bf[4];                                               \
    _Pragma("unroll")                                                  \
    for (int t_ = 0; t_ < 4; ++t_) {                                   \
      af[t_] = *(const short8*)&LA[(wm + t_ * 16 + l15) * 32 + sw];    \
      bf[t_] = *(const short8*)&LB[(wn + t_ * 16 + l15) * 32 + sw];    \
    }                                                                  \
    asm volatile("s_waitcnt lgkmcnt(0)" ::: "memory");                 \
    __builtin_amdgcn_s_barrier();                                      \
    if (STG) GSTAGE(LA, LB, OFF);                                      \
    __builtin_amdgcn_s_setprio(1);                                     \
    _Pragma("unroll")                                                  \
    for (int tm = 0; tm < 4; ++tm)                                     \
      _Pragma("unroll")                                                \
      for (int tn = 0; tn < 4; ++tn)                                   \
        acc[tm][tn] = MFMA16(af[tm], bf[tn], acc[tm][tn]);             \
    __builtin_amdgcn_s_setprio(0);                                     \
  } while (0)

// two steps t (buf0), t+1 (buf1), staging tiles t+2, t+3
#define GK2(T)                                                         \
  GSTEP(As0, Bs0, ((T) + 2) * 32, 1, 4);                               \
  GSTEP(As1, Bs1, ((T) + 3) * 32, 1, 4);

#define GEMM_KLOOP                                                     \
  GSTAGE(As0, Bs0, 0); GSTAGE(As1, Bs1, 32);                           \
  GK2(0) GK2(2) GK2(4) GK2(6) GK2(8) GK2(10)                           \
  GK2(12) GK2(14) GK2(16) GK2(18) GK2(20)                              \
  GSTEP(As0, Bs0, 0, 0, 4);                                            \
  GSTEP(As1, Bs1, 0, 0, 0);

#define GEMM_DECLS                                                     \
  __shared__ ushort_t As0[128 * 32], As1[128 * 32];                    \
  __shared__ ushort_t Bs0[128 * 32], Bs1[128 * 32];                    \
  const int tid  = threadIdx.x;                                        \
  const int lane = tid & 63;                                           \
  const int l15  = lane & 15;                                          \
  const int quad = lane >> 4;                                          \
  const int wid  = tid >> 6;                                           \
  const int m0 = blockIdx.x * 128;                                     \
  const int n0 = blockIdx.y * 128;                                     \
  const int wm = (wid >> 1) * 64;                                      \
  const int wn = (wid & 1) * 64;                                       \
  const int srow = tid >> 2;                                           \
  const int scol = (((tid & 3) ^ ((srow ^ (srow >> 2)) & 3))) * 8;     \
  const int sw = (quad ^ ((l15 ^ (l15 >> 2)) & 3)) * 8;                \
  floatx4 acc[4][4] = {};

// ---------------------------------------------------------------------------
// QKV GEMM: qkv = x @ Wqkv^T + b. Q columns pre-scaled by (1/sqrt(96))*log2e.
// Writes q,k into QK (row stride 1536) and v TRANSPOSED into VT[b][h][d][T]
// with time index sigma-permuted within each 64-block (attention needs no
// cross-lane P exchange).
// ---------------------------------------------------------------------------
__global__ __launch_bounds__(256) void gemm_qkv(
    const ushort_t* __restrict__ A,   // 8192 x 768 bf16 (x)
    const ushort_t* __restrict__ W,   // 2304 x 768 bf16
    const float* __restrict__ bias,   // 2304 f32
    ushort_t* __restrict__ QK,        // 8192 x 1536 bf16
    ushort_t* __restrict__ VT)        // (64 bh) x 96 x 1024 bf16 (perm cols)
{
  GEMM_DECLS;

  const ushort_t* gA = A + (size_t)(m0 + srow) * 768 + scol;
  const ushort_t* gB = W + (size_t)(n0 + srow) * 768 + scol;

  GEMM_KLOOP;

  const float QSCALE = 0.10206207261596577f * 1.4426950408889634f;

#pragma unroll
  for (int tn = 0; tn < 4; ++tn) {
    const int gc = n0 + wn + tn * 16 + l15;
    const float bv = bias[gc];
    const bool isv = (gc >= 1536);          // whole 16-col tile same side
    const bool isq = (gc < 768);
    const int hh = (gc - 1536) / 96, dd = (gc - 1536) % 96;
#pragma unroll
    for (int tm = 0; tm < 4; ++tm) {
      const int gr = m0 + wm + tm * 16 + quad * 4;
#pragma unroll
      for (int r = 0; r < 4; ++r) {
        float val = acc[tm][tn][r] + bv;
        const int row = gr + r;
        if (!isv) {
          if (isq) val *= QSCALE;
          QK[(size_t)row * 1536 + gc] = f2bf(val);
        } else {
          const int bb = row >> 10, tt = row & 1023;
          // sigma: bit2 <- tt.bit4, bits4..3 <- tt.bits3..2
          const int tt2 = (tt & ~0x1C) | (((tt >> 4) & 1) << 2) |
                          (((tt >> 2) & 3) << 3);
          VT[(((size_t)(bb * 8 + hh)) * 96 + dd) * 1024 + tt2] = f2bf(val);
        }
      }
    }
  }
}

// ---------------------------------------------------------------------------
// Generic GEMM (proj): C[m][n] = sum_k A[m][k] W[n][k] + bias[n], f32 out.
// K = 768 fixed. Same counted pipeline.
// ---------------------------------------------------------------------------
__global__ __launch_bounds__(256) void gemm_proj(
    const ushort_t* __restrict__ A,   // M x 768 bf16
    const ushort_t* __restrict__ W,   // N x 768 bf16
    const float* __restrict__ bias,   // N f32
    float* __restrict__ C,            // M x N f32
    int M, int N)
{
  GEMM_DECLS;

  const ushort_t* gA = A + (size_t)(m0 + srow) * 768 + scol;
  const ushort_t* gB = W + (size_t)(n0 + srow) * 768 + scol;

  GEMM_KLOOP;

#pragma unroll
  for (int tn = 0; tn < 4; ++tn) {
    const int gc = n0 + wn + tn * 16 + l15;
    const float bv = bias[gc];
#pragma unroll
    for (int tm = 0; tm < 4; ++tm) {
      const int gr = m0 + wm + tm * 16 + quad * 4;
#pragma unroll
      for (int r = 0; r < 4; ++r)
        C[(size_t)(gr + r) * N + gc] = acc[tm][tn][r] + bv;
    }
  }
}

// ---------------------------------------------------------------------------
// Fused causal flash attention, swapped-QK^T form, counted-vmcnt pipeline.
// R6 mapping: grid (16, 64); block = one 64-row q-chunk of one (b,h).
// chunk/bh derived from an XCD-swizzled linear id (8 consecutive bh per
// XCD -> K/V L2-resident). Waves own rows chunk*64 + wid*16; kend =
// (chunk+1)*64 so every wave is active in every iteration (no idle slots).
// ---------------------------------------------------------------------------
#define ATTN_COMPUTE(KS, VTC, K0)                                      \
  do {                                                                 \
    floatx4 s[4] = {};                                                 \
    __builtin_amdgcn_s_setprio(1);                                     \
    _Pragma("unroll")                                                  \
    for (int t = 0; t < 4; ++t) {                                      \
      _Pragma("unroll")                                                \
      for (int c = 0; c < 3; ++c) {                                    \
        short8 kf = *(const short8*)                                   \
            &KS[(t * 16 + l15) * 96 + c * 32 + quad * 8];              \
        s[t] = MFMA16(kf, qf[c], s[t]);                                \
      }                                                                \
    }                                                                  \
    __builtin_amdgcn_s_setprio(0);                                     \
    float p[4][4];                                                     \
    if ((K0) + 64 <= q0w) {                                            \
      _Pragma("unroll")                                                \
      for (int t = 0; t < 4; ++t)                                      \
        _Pragma("unroll")                                              \
        for (int j = 0; j < 4; ++j) p[t][j] = s[t][j];                 \
    } else {                                                           \
      const int kq = (K0) + quad * 4;                                  \
      _Pragma("unroll")                                                \
      for (int t = 0; t < 4; ++t)                                      \
        _Pragma("unroll")                                              \
        for (int j = 0; j < 4; ++j)                                    \
          p[t][j] = (kq + t * 16 + j <= rq) ? s[t][j] : NEG_BIG;       \
    }                                                                  \
    float m0v = fmaxf(fmaxf(p[0][0], p[0][1]), fmaxf(p[0][2], p[0][3]));\
    float m1v = fmaxf(fmaxf(p[1][0], p[1][1]), fmaxf(p[1][2], p[1][3]));\
    float m2v = fmaxf(fmaxf(p[2][0], p[2][1]), fmaxf(p[2][2], p[2][3]));\
    float m3v = fmaxf(fmaxf(p[3][0], p[3][1]), fmaxf(p[3][2], p[3][3]));\
    float mt = fmaxf(fmaxf(m0v, m1v), fmaxf(m2v, m3v));                \
    mt = fmaxf(mt, __shfl_xor(mt, 16));                                \
    mt = fmaxf(mt, __shfl_xor(mt, 32));                                \
    if (!__all(mt - m_i <= 8.0f)) {                                    \
      const float mn = fmaxf(m_i, mt);                                 \
      const float al = __builtin_amdgcn_exp2f(m_i - mn);               \
      m_i = mn;                                                        \
      l_i *= al;                                                       \
      _Pragma("unroll")                                                \
      for (int j = 0; j < 4; ++j) {                                    \
        const float alr = __shfl(al, quad * 4 + j);                    \
        _Pragma("unroll")                                              \
        for (int f = 0; f < 6; ++f) O[f][j] *= alr;                    \
      }                                                                \
    }                                                                  \
    float rs = 0.f;                                                    \
    _Pragma("unroll")                                                  \
    for (int t = 0; t < 4; ++t)                                        \
      _Pragma("unroll")                                                \
      for (int j = 0; j < 4; ++j) {                                    \
        p[t][j] = __builtin_amdgcn_exp2f(p[t][j] - m_i);               \
        rs += p[t][j];                                                 \
      }                                                                \
    rs += __shfl_xor(rs, 16);                                          \
    rs += __shfl_xor(rs, 32);                                          \
    l_i += rs;                                                         \
    union { short8 s8; unsigned int u[4]; } pf0, pf1;                  \
    pf0.u[0] = packbf2(p[0][0], p[0][1]);                              \
    pf0.u[1] = packbf2(p[0][2], p[0][3]);                              \
    pf0.u[2] = packbf2(p[1][0], p[1][1]);                              \
    pf0.u[3] = packbf2(p[1][2], p[1][3]);                              \
    pf1.u[0] = packbf2(p[2][0], p[2][1]);                              \
    pf1.u[1] = packbf2(p[2][2], p[2][3]);                              \
    pf1.u[2] = packbf2(p[3][0], p[3][1]);                              \
    pf1.u[3] = packbf2(p[3][2], p[3][3]);                              \
    __builtin_amdgcn_s_setprio(1);                                     \
    _Pragma("unroll")                                                  \
    for (int f = 0; f < 6; ++f) {                                      \
      short8 vf0 = *(const short8*)&VTC[(f * 16 + l15) * 72 + quad * 8];\
      O[f] = MFMA16(pf0.s8, vf0, O[f]);                                \
      short8 vf1 = *(const short8*)                                    \
          &VTC[(f * 16 + l15) * 72 + 32 + quad * 8];                   \
      O[f] = MFMA16(pf1.s8, vf1, O[f]);                                \
    }                                                                  \
    __builtin_amdgcn_s_setprio(0);                                     \
  } while (0)

// one pipelined iteration (never the last): wait, stage K(t+1) into KSN,
// compute(t) from KS/VTC, write V(t+1) into VTN, load V(t+2) regs.
#define AITER(KS, VTC, KSN, VTN, K0)                                   \
  do {                                                                 \
    const int k0_ = (K0);                                              \
    const int nk_ = k0_ + 64;                                          \
    WAITBAR_LGKM(3);                                                   \
    _Pragma("unroll")                                                  \
    for (int i = 0; i < 3; ++i) {                                      \
      const int e = ke0 + i * 512;                                     \
      const int kr = e / 96, kc = e % 96;                              \
      GLOAD16(QK + (rowbase + nk_ + kr) * 1536 + 768 + qoff + kc,      \
              &KSN[wid * 1536 + i * 512]);                             \
    }                                                                  \
    ATTN_COMPUTE(KS, VTC, k0_);                                        \
    _Pragma("unroll")                                                  \
    for (int g = 0; g < 3; ++g)                                        \
      *(short8*)&VTN[(g * 32 + vd) * 72 + vkc] = vreg[g];              \
    if (nk_ + 64 < kend) {                                             \
      _Pragma("unroll")                                                \
      for (int g = 0; g < 3; ++g)                                      \
        vreg[g] = *(const short8*)                                     \
            (vtb + (size_t)(g * 32 + vd) * 1024 + nk_ + 64 + vkc);     \
    }                                                                  \
  } while (0)

#define AITER_LAST(KS, VTC, K0)                                        \
  do {                                                                 \
    WAITBAR_LGKM(0);                                                   \
    ATTN_COMPUTE(KS, VTC, (K0));                                       \
  } while (0)

__global__ __launch_bounds__(256) void attn_fused(
    const ushort_t* __restrict__ QK,   // (B*T) x 1536 bf16  [q*scale | k]
    const ushort_t* __restrict__ VT,   // (64 bh) x 96 x 1024 bf16 (perm cols)
    ushort_t* __restrict__ y)          // (B*T) x 768 bf16
{
  __shared__ ushort_t Ks0[64 * 96], Ks1[64 * 96];
  __shared__ ushort_t Vt0[96 * 72], Vt1[96 * 72];

  const int tid  = threadIdx.x;
  const int lane = tid & 63;
  const int l15  = lane & 15;
  const int quad = lane >> 4;
  const int wid  = tid >> 6;

  // XCD-swizzled work assignment: linear id -> (chunk, bh); 1024 = 128 x 8,
  // XCD c (= lin % 8) gets bh in [c*8, c*8+8) for all 16 chunks.
  const int lin = blockIdx.x + (blockIdx.y << 4);
  const int swz = ((lin & 7) << 7) + (lin >> 3);
  const int chunk = swz & 15;          // 0..15 (q rows chunk*64 .. +63)
  const int bh = swz >> 4;             // 0..63
  const int b = bh >> 3;
  const int h = bh & 7;
  const int qoff = h * 96;

  const int q0w = chunk * 64 + wid * 16;   // wave's first q row
  const int kend = chunk * 64 + 64;        // block loop bound == causal bound
  const int rq = q0w + l15;                // this lane's q row

  const size_t rowbase = (size_t)b * 1024;
  const ushort_t* vtb = VT + (size_t)bh * 96 * 1024;

  // per-thread staging coords
  const int ke0 = wid * 1536 + lane * 8;           // K-stage element base
  const int vd  = (tid >> 3);                      // V-stage row within group
  const int vkc = (tid & 7) * 8;                   // V-stage col

  // Q fragments (used as B operand), K=96 in 3 chunks of 32
  short8 qf[3];
#pragma unroll
  for (int c = 0; c < 3; ++c)
    qf[c] = *(const short8*)(QK + (rowbase + q0w + l15) * 1536 + qoff +
                             c * 32 + quad * 8);

  float m_i = NEG_BIG;   // running max for row l15 (exp2 domain)
  float l_i = 0.f;       // running denom for row l15
  floatx4 O[6] = {};

  short8 vreg[3];

  // prologue: V(0) regs FIRST, K(0) gloads, write V(0), issue V(1) regs.
#pragma unroll
  for (int g = 0; g < 3; ++g)
    vreg[g] = *(const short8*)(vtb + (size_t)(g * 32 + vd) * 1024 + vkc);
#pragma unroll
  for (int i = 0; i < 3; ++i) {
    const int e = ke0 + i * 512;
    const int kr = e / 96, kc = e % 96;
    GLOAD16(QK + (rowbase + kr) * 1536 + 768 + qoff + kc,
            &Ks0[wid * 1536 + i * 512]);
  }
#pragma unroll
  for (int g = 0; g < 3; ++g)
    *(short8*)&Vt0[(g * 32 + vd) * 72 + vkc] = vreg[g];
#pragma unroll
  for (int g = 0; g < 3; ++g)
    vreg[g] = *(const short8*)(vtb + (size_t)(g * 32 + vd) * 1024 + 64 + vkc);

  // main loop: pairs of tiles with static buffers; 1-or-2 iteration tail.
  int k0 = 0;
  while (k0 + 128 < kend) {
    AITER(Ks0, Vt0, Ks1, Vt1, k0);
    AITER(Ks1, Vt1, Ks0, Vt0, k0 + 64);
    k0 += 128;
  }
  if (k0 + 64 < kend) {
    AITER(Ks0, Vt0, Ks1, Vt1, k0);
    AITER_LAST(Ks1, Vt1, k0 + 64);
  } else {
    AITER_LAST(Ks0, Vt0, k0);
  }

  // epilogue: O rows are quad*4+j; softmax denom lives in lane (row)
  float inv[4];
#pragma unroll
  for (int j = 0; j < 4; ++j) {
    const float lj = __shfl(l_i, quad * 4 + j);
    inv[j] = 1.0f / fmaxf(lj, 1e-20f);
  }
#pragma unroll
  for (int j = 0; j < 4; ++j) {
    const size_t row = rowbase + q0w + quad * 4 + j;
#pragma unroll
    for (int f = 0; f < 6; ++f)
      y[row * 768 + qoff + f * 16 + l15] = f2bf(O[f][j] * inv[j]);
  }
}

// ---------------------------------------------------------------------------
extern "C" void kernel_launch(void* const* d_in, const int* in_sizes, int n_in,
                              void* d_out, int out_size, void* d_ws, size_t ws_size,
                              hipStream_t stream)
{
  const float* x_f  = (const float*)d_in[0];
  const float* wa_f = (const float*)d_in[1];
  const float* ba_f = (const float*)d_in[2];
  const float* wp_f = (const float*)d_in[3];
  const float* bp_f = (const float*)d_in[4];
  float* out = (float*)d_out;

  ushort_t* xb  = (ushort_t*)d_ws;                    // 8192 x  768
  ushort_t* wab = xb  + (size_t)8192 * 768;           // 2304 x  768
  ushort_t* wpb = wab + (size_t)2304 * 768;           //  768 x  768
  ushort_t* QK  = wpb + (size_t)768 * 768;            // 8192 x 1536
  ushort_t* VT  = QK  + (size_t)8192 * 1536;          // 64 x 96 x 1024
  ushort_t* yw  = VT  + (size_t)8192 * 768;           // 8192 x  768

  // (8192*768 + 2304*768 + 768*768)/4 = 2162688 = 8448 * 256
  cvt3<<<8448, 256, 0, stream>>>(x_f, wa_f, wp_f, xb, wab, wpb);

  gemm_qkv<<<dim3(64, 18), 256, 0, stream>>>(xb, wab, ba_f, QK, VT);
  attn_fused<<<dim3(16, 64), 256, 0, stream>>>(QK, VT, yw);
  gemm_proj<<<dim3(64, 6), 256, 0, stream>>>(yw, wpb, bp_f, out,
                                             8192, 768);
}